// Round 10
// baseline (62.628 us; speedup 1.0000x reference)
//
#include <hip/hip_runtime.h>
#include <math.h>

#define NN 8192
#define HH 128
#define LRELU_ALPHA 0.2f
#define R_ROWS 32           // rows with t_i >= 2^-32; truncation error < 2e-9
#define I0 (NN - R_ROWS)    // 8160

// u-prelude: compute u1 = W@a1, u2 = W@a2 into LDS (256 threads, 2 per k)
__device__ __forceinline__ void u_prelude(const float* __restrict__ W,
                                          const float* __restrict__ a,
                                          float* u1s, float* u2s, int tid) {
    int k = tid >> 1, half = tid & 1;
    const float4* wrow = (const float4*)(W + (size_t)k * HH + half * 64);
    const float4* a1v  = (const float4*)(a + half * 64);
    const float4* a2v  = (const float4*)(a + HH + half * 64);
    float p1 = 0.f, p2 = 0.f;
    #pragma unroll
    for (int q = 0; q < 16; q++) {
        float4 wv = wrow[q], b1 = a1v[q], b2 = a2v[q];
        p1 += wv.x * b1.x + wv.y * b1.y + wv.z * b1.z + wv.w * b1.w;
        p2 += wv.x * b2.x + wv.y * b2.y + wv.z * b2.z + wv.w * b2.w;
    }
    p1 += __shfl_xor(p1, 1);
    p2 += __shfl_xor(p2, 1);
    if (half == 0) { u1s[k] = p1; u2s[k] = p2; }
}

// ---------- K1: Zpart[ii][p] = partial sum over 1024-j chunk of masked e^s ----
__global__ __launch_bounds__(256) void k_z(const int* __restrict__ A,
                                           const float* __restrict__ inp,
                                           const float* __restrict__ W,
                                           const float* __restrict__ a,
                                           float* __restrict__ Zpart) {
    const int b = blockIdx.x;            // 256 = 32 rows x 8 chunks
    const int ii = b >> 3, p = b & 7;
    const int i = I0 + ii;
    const int tid = threadIdx.x, wave = tid >> 6, lane = tid & 63;
    __shared__ float u1s[HH], u2s[HH];
    __shared__ float red[4];
    __shared__ float f1i_s;

    u_prelude(W, a, u1s, u2s, tid);
    __syncthreads();

    if (wave == 0) {    // f1_i = inp[i] @ u1
        float2 x = ((const float2*)(inp + (size_t)i * HH))[lane];
        float2 u = ((const float2*)u1s)[lane];
        float pp = x.x * u.x + x.y * u.y;
        for (int off = 32; off; off >>= 1) pp += __shfl_down(pp, off);
        if (lane == 0) f1i_s = pp;
    }
    __syncthreads();
    const float f1i = f1i_s;

    // this thread's 4 j's
    const int j0 = p * 1024 + tid * 4;
    const int4 av = *(const int4*)(A + (size_t)i * NN + j0);
    const float4* u2v = (const float4*)u2s;

    float fj[4];
    #pragma unroll
    for (int c = 0; c < 4; c++) {
        const float4* row = (const float4*)(inp + (size_t)(j0 + c) * HH);
        float acc = 0.f;
        #pragma unroll
        for (int q = 0; q < 32; q++) {
            float4 xv = row[q], uv = u2v[q];
            acc += xv.x * uv.x + xv.y * uv.y + xv.z * uv.z + xv.w * uv.w;
        }
        fj[c] = acc;
    }
    const int va[4] = {av.x, av.y, av.z, av.w};
    float z = 0.f;
    #pragma unroll
    for (int c = 0; c < 4; c++) {
        float x = f1i + fj[c];
        x = x > 0.f ? x : LRELU_ALPHA * x;
        z += ((va[c] > 0) || (j0 + c == i)) ? __expf(x) : 0.f;
    }
    for (int off = 32; off; off >>= 1) z += __shfl_xor(z, off);
    if (lane == 0) red[wave] = z;
    __syncthreads();
    if (tid == 0) Zpart[b] = red[0] + red[1] + red[2] + red[3];
}

// ---------- K2: w_j (64 j's/block) -> vfin -> hpart_b = vfin @ W --------------
__global__ __launch_bounds__(256) void k_wv(const int* __restrict__ A,
                                            const float* __restrict__ inp,
                                            const float* __restrict__ W,
                                            const float* __restrict__ a,
                                            const float* __restrict__ Zpart,
                                            float* __restrict__ hpart) {
    const int b = blockIdx.x;          // 128 blocks
    const int jbase = b * 64;
    const int tid = threadIdx.x;
    __shared__ float u1s[HH], u2s[HH];
    __shared__ float red[256];
    __shared__ float wj[64];
    __shared__ float f1s[R_ROWS], czs[R_ROWS], f2s[64];
    __shared__ float vfin[128];

    u_prelude(W, a, u1s, u2s, tid);
    __syncthreads();

    // f2s[jj] = inp[jbase+jj] @ u2  (4 threads per j, quarter dots)
    {
        int jj = tid >> 2, q = tid & 3;
        const float4* row = (const float4*)(inp + (size_t)(jbase + jj) * HH + q * 32);
        const float4* u2v = (const float4*)(u2s + q * 32);
        float acc = 0.f;
        #pragma unroll
        for (int t = 0; t < 8; t++) {
            float4 x = row[t], u = u2v[t];
            acc += x.x * u.x + x.y * u.y + x.z * u.z + x.w * u.w;
        }
        acc += __shfl_xor(acc, 1);
        acc += __shfl_xor(acc, 2);
        if (q == 0) f2s[jj] = acc;
    }
    // f1s + czs (threads 0..31)
    if (tid < R_ROWS) {
        const float4* row = (const float4*)(inp + (size_t)(I0 + tid) * HH);
        const float4* u1v = (const float4*)u1s;
        float acc = 0.f;
        #pragma unroll
        for (int q = 0; q < 32; q++) {
            float4 x = row[q], u = u1v[q];
            acc += x.x * u.x + x.y * u.y + x.z * u.z + x.w * u.w;
        }
        f1s[tid] = acc;
        float Z = 0.f;
        #pragma unroll
        for (int p = 0; p < 8; p++) Z += Zpart[tid * 8 + p];
        czs[tid] = exp2f((float)(tid - R_ROWS)) / Z;   // t_i / Z'_i
    }
    __syncthreads();

    // w_j over 32 rows (4 i-groups x 64 j-lanes, 8 iterations)
    const int jj = tid & 63, ic = tid >> 6;
    const int j = jbase + jj;
    const float f2j = f2s[jj];
    float w = 0.f;
    #pragma unroll
    for (int q = 0; q < R_ROWS / 4; q++) {
        int ii = q * 4 + ic;
        int av = A[(size_t)(I0 + ii) * NN + j];
        float x = f1s[ii] + f2j;
        x = x > 0.f ? x : LRELU_ALPHA * x;
        float e = __expf(x);
        w += ((av > 0) || (j == I0 + ii)) ? czs[ii] * e : 0.f;
    }
    red[ic * 64 + jj] = w;
    __syncthreads();
    if (tid < 64) wj[tid] = red[tid] + red[64 + tid] + red[128 + tid] + red[192 + tid];
    __syncthreads();

    // weighted sum of inp rows for this j-range -> vfin[128]
    int k = tid & 127, half = tid >> 7;
    float v = 0.f;
    for (int j2 = half; j2 < 64; j2 += 2)
        v += wj[j2] * inp[(size_t)(jbase + j2) * HH + k];
    red[tid] = v;
    __syncthreads();
    if (half == 0) vfin[k] = red[k] + red[128 + k];
    __syncthreads();

    // hpart_b[e] = sum_k vfin[k] * W[k][e]
    float h = 0.f;
    for (int kk = half; kk < HH; kk += 2)
        h += vfin[kk] * W[(size_t)kk * HH + k];
    red[tid] = h;
    __syncthreads();
    if (half == 0) hpart[(size_t)b * HH + k] = red[k] + red[128 + k];
}

// ---------- K3: h_t = sum_b hpart_b; out = elu(h_t) ----------
__global__ __launch_bounds__(256) void k_final(const float* __restrict__ hpart,
                                               float* __restrict__ out) {
    __shared__ float4 red4[256];
    const int tid = threadIdx.x;
    const int e4 = tid & 31, g = tid >> 5;    // 8 groups x 32 float4-slots
    const float4* hp4 = (const float4*)hpart;
    float4 acc = {0.f, 0.f, 0.f, 0.f};
    for (int b = g; b < 128; b += 8) {
        float4 x = hp4[(size_t)b * 32 + e4];
        acc.x += x.x; acc.y += x.y; acc.z += x.z; acc.w += x.w;
    }
    red4[g * 32 + e4] = acc;
    __syncthreads();
    if (tid < 32) {
        float4 h = red4[tid];
        #pragma unroll
        for (int gg = 1; gg < 8; gg++) {
            float4 x = red4[gg * 32 + tid];
            h.x += x.x; h.y += x.y; h.z += x.z; h.w += x.w;
        }
        h.x = h.x > 0.f ? h.x : expm1f(h.x);
        h.y = h.y > 0.f ? h.y : expm1f(h.y);
        h.z = h.z > 0.f ? h.z : expm1f(h.z);
        h.w = h.w > 0.f ? h.w : expm1f(h.w);
        ((float4*)out)[tid] = h;
    }
}

extern "C" void kernel_launch(void* const* d_in, const int* in_sizes, int n_in,
                              void* d_out, int out_size, void* d_ws, size_t ws_size,
                              hipStream_t stream) {
    const float* inp = (const float*)d_in[0];   // [8192,128] f32
    const int*   A   = (const int*)d_in[1];     // [8192,8192] i32
    const float* W   = (const float*)d_in[2];   // [128,128] f32
    const float* a   = (const float*)d_in[3];   // [256,1] f32
    float* out = (float*)d_out;                 // [128] f32
    float* ws  = (float*)d_ws;

    // workspace layout (floats)
    float* Zpart = ws;               // 256 (32 rows x 8 chunks)
    float* hpart = ws + 256;         // 128*128

    k_z    <<<R_ROWS * 8, 256, 0, stream>>>(A, inp, W, a, Zpart);
    k_wv   <<<128,        256, 0, stream>>>(A, inp, W, a, Zpart, hpart);
    k_final<<<1,          256, 0, stream>>>(hpart, out);
}

// Round 11
// 30.153 us; speedup vs baseline: 2.0770x; 2.0770x over previous
//
#include <hip/hip_runtime.h>
#include <math.h>

#define NN 8192
#define HH 128
#define LRELU_ALPHA 0.2f
#define R_ROWS 32           // rows with t_i >= 2^-32; truncation error < 2e-9
#define I0 (NN - R_ROWS)    // 8160
#define JBLK 128            // j-chunks (64 j's each)

// u-prelude: compute u1 = W@a1, u2 = W@a2 into LDS (256 threads, 2 per k)
__device__ __forceinline__ void u_prelude(const float* __restrict__ W,
                                          const float* __restrict__ a,
                                          float* u1s, float* u2s, int tid) {
    int k = tid >> 1, half = tid & 1;
    const float4* wrow = (const float4*)(W + (size_t)k * HH + half * 64);
    const float4* a1v  = (const float4*)(a + half * 64);
    const float4* a2v  = (const float4*)(a + HH + half * 64);
    float p1 = 0.f, p2 = 0.f;
    #pragma unroll
    for (int q = 0; q < 16; q++) {
        float4 wv = wrow[q], b1 = a1v[q], b2 = a2v[q];
        p1 += wv.x * b1.x + wv.y * b1.y + wv.z * b1.z + wv.w * b1.w;
        p2 += wv.x * b2.x + wv.y * b2.y + wv.z * b2.z + wv.w * b2.w;
    }
    p1 += __shfl_xor(p1, 1);
    p2 += __shfl_xor(p2, 1);
    if (half == 0) { u1s[k] = p1; u2s[k] = p2; }
}

// ---------- K1: per 64-j chunk: masked e^s tile + Zpart --------------------
// et[(p*32 + ii)*64 + jj] = masked exp(s_ij); Zpart[ii*JBLK + p] = partial Z
__global__ __launch_bounds__(256) void k_zw(const int* __restrict__ A,
                                            const float* __restrict__ inp,
                                            const float* __restrict__ W,
                                            const float* __restrict__ a,
                                            float* __restrict__ et,
                                            float* __restrict__ Zpart) {
    const int p = blockIdx.x;            // 0..127
    const int jbase = p * 64;
    const int tid = threadIdx.x;
    __shared__ float u1s[HH], u2s[HH];
    __shared__ float f1s[R_ROWS], f2s[64];

    u_prelude(W, a, u1s, u2s, tid);
    __syncthreads();

    // f2s[jj] = inp[jbase+jj] @ u2  (4 threads per j, quarter dots)
    {
        int jj = tid >> 2, q = tid & 3;
        const float4* row = (const float4*)(inp + (size_t)(jbase + jj) * HH + q * 32);
        const float4* u2v = (const float4*)(u2s + q * 32);
        float acc = 0.f;
        #pragma unroll
        for (int t = 0; t < 8; t++) {
            float4 x = row[t], u = u2v[t];
            acc += x.x * u.x + x.y * u.y + x.z * u.z + x.w * u.w;
        }
        acc += __shfl_xor(acc, 1);
        acc += __shfl_xor(acc, 2);
        if (q == 0) f2s[jj] = acc;
    }
    // f1s (threads 0..31, small)
    if (tid < R_ROWS) {
        const float4* row = (const float4*)(inp + (size_t)(I0 + tid) * HH);
        const float4* u1v = (const float4*)u1s;
        float acc = 0.f;
        #pragma unroll
        for (int q = 0; q < 32; q++) {
            float4 x = row[q], u = u1v[q];
            acc += x.x * u.x + x.y * u.y + x.z * u.z + x.w * u.w;
        }
        f1s[tid] = acc;
    }
    __syncthreads();

    // e-tile: thread handles (ii = tid>>3, 8 j's at jj0 = (tid&7)*8)
    const int ii = tid >> 3, s = tid & 7;
    const int jj0 = s * 8;
    const int i = I0 + ii;
    const int* arow = A + (size_t)i * NN + jbase + jj0;
    const int4 av0 = *(const int4*)(arow);
    const int4 av1 = *(const int4*)(arow + 4);
    const int va[8] = {av0.x, av0.y, av0.z, av0.w, av1.x, av1.y, av1.z, av1.w};
    const float f1i = f1s[ii];

    float e[8];
    float z = 0.f;
    #pragma unroll
    for (int c = 0; c < 8; c++) {
        float x = f1i + f2s[jj0 + c];
        x = x > 0.f ? x : LRELU_ALPHA * x;
        float ev = ((va[c] > 0) || (jbase + jj0 + c == i)) ? __expf(x) : 0.f;
        e[c] = ev;
        z += ev;
    }
    // 8-lane reduce for Zpart
    z += __shfl_xor(z, 1);
    z += __shfl_xor(z, 2);
    z += __shfl_xor(z, 4);
    if (s == 0) Zpart[(size_t)ii * JBLK + p] = z;

    float* eout = et + ((size_t)p * R_ROWS + ii) * 64 + jj0;
    *(float4*)(eout)     = make_float4(e[0], e[1], e[2], e[3]);
    *(float4*)(eout + 4) = make_float4(e[4], e[5], e[6], e[7]);
}

// ---------- K2: Z reduce -> w_j -> vfin -> hpart_b = vfin @ W -----------------
__global__ __launch_bounds__(256) void k_wv(const float* __restrict__ inp,
                                            const float* __restrict__ W,
                                            const float* __restrict__ et,
                                            const float* __restrict__ Zpart,
                                            float* __restrict__ hpart) {
    const int b = blockIdx.x;          // 128 blocks
    const int jbase = b * 64;
    const int tid = threadIdx.x;
    __shared__ float red[256];
    __shared__ float wj[64];
    __shared__ float czs[R_ROWS];
    __shared__ float vfin[128];

    // czs[ii] = t_ii / Z_ii ; Z_ii = sum_p Zpart[ii*JBLK+p]  (8 threads per ii)
    {
        int ii = tid >> 3, s = tid & 7;
        const float4* zp = (const float4*)(Zpart + (size_t)ii * JBLK + s * 16);
        float zsum = 0.f;
        #pragma unroll
        for (int q = 0; q < 4; q++) {
            float4 zv = zp[q];
            zsum += zv.x + zv.y + zv.z + zv.w;
        }
        zsum += __shfl_xor(zsum, 1);
        zsum += __shfl_xor(zsum, 2);
        zsum += __shfl_xor(zsum, 4);
        if (s == 0) czs[ii] = exp2f((float)(ii - R_ROWS)) / zsum;
    }
    __syncthreads();

    // w_j over 32 rows from the e-tile (4 i-groups x 64 j-lanes, 8 iterations)
    const int jj = tid & 63, ic = tid >> 6;
    float w = 0.f;
    #pragma unroll
    for (int q = 0; q < R_ROWS / 4; q++) {
        int ii = q * 4 + ic;
        w += czs[ii] * et[((size_t)b * R_ROWS + ii) * 64 + jj];
    }
    red[ic * 64 + jj] = w;
    __syncthreads();
    if (tid < 64) wj[tid] = red[tid] + red[64 + tid] + red[128 + tid] + red[192 + tid];
    __syncthreads();

    // weighted sum of inp rows for this j-range -> vfin[128]
    int k = tid & 127, half = tid >> 7;
    float v = 0.f;
    for (int j2 = half; j2 < 64; j2 += 2)
        v += wj[j2] * inp[(size_t)(jbase + j2) * HH + k];
    red[tid] = v;
    __syncthreads();
    if (half == 0) vfin[k] = red[k] + red[128 + k];
    __syncthreads();

    // hpart_b[e] = sum_k vfin[k] * W[k][e]
    float h = 0.f;
    for (int kk = half; kk < HH; kk += 2)
        h += vfin[kk] * W[(size_t)kk * HH + k];
    red[tid] = h;
    __syncthreads();
    if (half == 0) hpart[(size_t)b * HH + k] = red[k] + red[128 + k];
}

// ---------- K3: h_t = sum_b hpart_b; out = elu(h_t) ----------
__global__ __launch_bounds__(256) void k_final(const float* __restrict__ hpart,
                                               float* __restrict__ out) {
    __shared__ float4 red4[256];
    const int tid = threadIdx.x;
    const int e4 = tid & 31, g = tid >> 5;    // 8 groups x 32 float4-slots
    const float4* hp4 = (const float4*)hpart;
    float4 acc = {0.f, 0.f, 0.f, 0.f};
    for (int b = g; b < 128; b += 8) {
        float4 x = hp4[(size_t)b * 32 + e4];
        acc.x += x.x; acc.y += x.y; acc.z += x.z; acc.w += x.w;
    }
    red4[g * 32 + e4] = acc;
    __syncthreads();
    if (tid < 32) {
        float4 h = red4[tid];
        #pragma unroll
        for (int gg = 1; gg < 8; gg++) {
            float4 x = red4[gg * 32 + tid];
            h.x += x.x; h.y += x.y; h.z += x.z; h.w += x.w;
        }
        h.x = h.x > 0.f ? h.x : expm1f(h.x);
        h.y = h.y > 0.f ? h.y : expm1f(h.y);
        h.z = h.z > 0.f ? h.z : expm1f(h.z);
        h.w = h.w > 0.f ? h.w : expm1f(h.w);
        ((float4*)out)[tid] = h;
    }
}

extern "C" void kernel_launch(void* const* d_in, const int* in_sizes, int n_in,
                              void* d_out, int out_size, void* d_ws, size_t ws_size,
                              hipStream_t stream) {
    const float* inp = (const float*)d_in[0];   // [8192,128] f32
    const int*   A   = (const int*)d_in[1];     // [8192,8192] i32
    const float* W   = (const float*)d_in[2];   // [128,128] f32
    const float* a   = (const float*)d_in[3];   // [256,1] f32
    float* out = (float*)d_out;                 // [128] f32
    float* ws  = (float*)d_ws;

    // workspace layout (floats)
    float* Zpart = ws;                          // 32*128 = 4096
    float* et    = ws + 4096;                   // 128*32*64 = 262144
    float* hpart = et + (size_t)JBLK * R_ROWS * 64;  // 128*128

    k_zw   <<<JBLK, 256, 0, stream>>>(A, inp, W, a, et, Zpart);
    k_wv   <<<JBLK, 256, 0, stream>>>(inp, W, et, Zpart, hpart);
    k_final<<<1,    256, 0, stream>>>(hpart, out);
}